// Round 5
// baseline (129.430 us; speedup 1.0000x reference)
//
#include <hip/hip_runtime.h>
#include <stdint.h>

typedef short bf16x8 __attribute__((ext_vector_type(8)));
typedef float f32x4  __attribute__((ext_vector_type(4)));

__device__ __forceinline__ unsigned short f2bf(float f) {
    unsigned int u = __float_as_uint(f);
    u += 0x7FFFu + ((u >> 16) & 1u);
    return (unsigned short)(u >> 16);
}
__device__ __forceinline__ float bf2f(unsigned short h) {
    return __uint_as_float(((unsigned int)h) << 16);
}

// ---- kernel A: fold W1f = w1@wf, W2f = w2@wf (store transposed bf16), cb = b@wf ----
__global__ void fuse_weights(const float* __restrict__ w1, const float* __restrict__ b1,
                             const float* __restrict__ w2, const float* __restrict__ b2,
                             const float* __restrict__ wf,
                             unsigned short* __restrict__ wcT,  // [2][128 cols][128 k]
                             float* __restrict__ cb)            // [2][128]
{
    int mat = blockIdx.x / 129;
    int kk  = blockIdx.x % 129;
    int c   = threadIdx.x;
    const float* w = (mat == 0) ? w1 : w2;
    const float* b = (mat == 0) ? b1 : b2;
    float acc = 0.f;
    if (kk < 128) {
        #pragma unroll 8
        for (int j = 0; j < 128; ++j) acc += w[kk * 128 + j] * wf[j * 128 + c];
        wcT[mat * 16384 + c * 128 + kk] = f2bf(acc);
    } else {
        #pragma unroll 8
        for (int j = 0; j < 128; ++j) acc += b[j] * wf[j * 128 + c];
        cb[mat * 128 + c] = acc;
    }
}

// ---- kernel B: g[mat] = x @ Wc[mat] + cb[mat] -> bf16 [2][nrows][128] ----
// WAVE_ROWS=32: ~3128 waves (12/CU) to hide the cold x-load latency.
#define WAVE_ROWS 32
__global__ __launch_bounds__(256) void gemm_g(
    const float* __restrict__ x, const unsigned short* __restrict__ wcT,
    const float* __restrict__ cb, unsigned short* __restrict__ g, int nrows)
{
    int lane = threadIdx.x & 63;
    int wid  = threadIdx.x >> 6;
    int r0   = (blockIdx.x * 4 + wid) * WAVE_ROWS;
    if (r0 >= nrows) return;
    int lrow = lane & 15;
    int kg   = lane >> 4;

    bf16x8 xf[2][4];   // [rowtile][kstep]
    #pragma unroll
    for (int t = 0; t < 2; ++t) {
        int row = r0 + t * 16 + lrow;
        bool v  = row < nrows;
        #pragma unroll
        for (int ks = 0; ks < 4; ++ks) {
            int k0 = ks * 32 + kg * 8;
            f32x4 p0 = v ? __builtin_nontemporal_load((const f32x4*)(x + (size_t)row * 128 + k0))
                         : f32x4{0,0,0,0};
            f32x4 p1 = v ? __builtin_nontemporal_load((const f32x4*)(x + (size_t)row * 128 + k0 + 4))
                         : f32x4{0,0,0,0};
            bf16x8 f;
            f[0] = (short)f2bf(p0[0]); f[1] = (short)f2bf(p0[1]);
            f[2] = (short)f2bf(p0[2]); f[3] = (short)f2bf(p0[3]);
            f[4] = (short)f2bf(p1[0]); f[5] = (short)f2bf(p1[1]);
            f[6] = (short)f2bf(p1[2]); f[7] = (short)f2bf(p1[3]);
            xf[t][ks] = f;
        }
    }

    #pragma unroll
    for (int mat = 0; mat < 2; ++mat) {
        unsigned short* gm = g + (size_t)mat * nrows * 128;
        const unsigned short* wT = wcT + mat * 16384;
        #pragma unroll 2
        for (int c = 0; c < 8; ++c) {
            bf16x8 wfr[4];
            const unsigned short* wb = wT + (size_t)(c * 16 + lrow) * 128 + kg * 8;
            #pragma unroll
            for (int ks = 0; ks < 4; ++ks)
                wfr[ks] = *(const bf16x8*)(wb + ks * 32);
            f32x4 acc[2];
            #pragma unroll
            for (int t = 0; t < 2; ++t) acc[t] = f32x4{0,0,0,0};
            #pragma unroll
            for (int ks = 0; ks < 4; ++ks) {
                #pragma unroll
                for (int t = 0; t < 2; ++t)
                    acc[t] = __builtin_amdgcn_mfma_f32_16x16x32_bf16(wfr[ks], xf[t][ks], acc[t], 0,0,0);
            }
            float4 bias = *(const float4*)(cb + mat * 128 + c * 16 + kg * 4);
            #pragma unroll
            for (int t = 0; t < 2; ++t) {
                int xrow = r0 + t * 16 + lrow;
                if (xrow < nrows) {
                    ushort4 o;
                    o.x = f2bf(acc[t][0] + bias.x); o.y = f2bf(acc[t][1] + bias.y);
                    o.z = f2bf(acc[t][2] + bias.z); o.w = f2bf(acc[t][3] + bias.w);
                    *(ushort4*)(gm + (size_t)xrow * 128 + c * 16 + kg * 4) = o;
                }
            }
        }
    }
}

// ---- kernel C: 2 nodes per wave (half-wave each), 4 dims/lane, float4 nt stores ----
__global__ __launch_bounds__(256) void gather_out(
    const int* __restrict__ ci, const unsigned short* __restrict__ g,
    const float* __restrict__ bfv, float* __restrict__ out,
    float* __restrict__ maskout, int nnodes)
{
    int wv   = (int)((blockIdx.x * blockDim.x + threadIdx.x) >> 6);
    int lane = threadIdx.x & 63;
    int half = lane >> 5;          // node within wave
    int hl   = lane & 31;          // lane within half-wave
    int n    = wv * 2 + half;
    bool nv  = n < nnodes;
    int nc   = nv ? n : (nnodes - 1);

    int civ = ci[nc * 8 + (hl & 7)];
    unsigned long long bal = __ballot(civ == -1);
    int cnt = __popcll((bal >> (half * 32)) & 0xFFull);
    int deg = (cnt == 8) ? 0 : (7 - cnt);      // half-wave-uniform

    int d = hl * 4;                // 4 dims/lane, 32 lanes cover 128
    float4 bfd = *(const float4*)(bfv + d);
    const unsigned short* g1 = g;
    const unsigned short* g2 = g + (size_t)nnodes * 128;

    // load phase: all gathers issued before any consumption.
    // ua[j] <- g1[civ[j]]   iff j < deg
    // ub[j] <- g2[civ[j+1]] iff deg>=2 && j < deg
    uint2 ua[7], ub[7];
    bool two = (deg >= 2);
    #pragma unroll
    for (int j = 0; j < 7; ++j) {
        int i0 = __shfl(civ, half * 32 + j);
        bool m = nv && (j < deg);
        ua[j] = m ? *(const uint2*)(g1 + (size_t)i0 * 128 + d) : uint2{0u, 0u};
    }
    #pragma unroll
    for (int j = 0; j < 7; ++j) {
        int i1 = __shfl(civ, half * 32 + j + 1);
        bool m = nv && two && (j < deg);
        ub[j] = m ? *(const uint2*)(g2 + (size_t)i1 * 128 + d) : uint2{0u, 0u};
    }

    // consume + store (branch-free adds; zero bits are exact no-ops)
    size_t outbase = (size_t)nc * 7 * 128;
    #pragma unroll
    for (int j = 0; j < 7; ++j) {
        f32x4 o;
        o[0] = bfd.x + bf2f((unsigned short)(ua[j].x & 0xFFFFu)) + bf2f((unsigned short)(ub[j].x & 0xFFFFu));
        o[1] = bfd.y + bf2f((unsigned short)(ua[j].x >> 16))     + bf2f((unsigned short)(ub[j].x >> 16));
        o[2] = bfd.z + bf2f((unsigned short)(ua[j].y & 0xFFFFu)) + bf2f((unsigned short)(ub[j].y & 0xFFFFu));
        o[3] = bfd.w + bf2f((unsigned short)(ua[j].y >> 16))     + bf2f((unsigned short)(ub[j].y >> 16));
        if (nv)
            __builtin_nontemporal_store(o, (f32x4*)(out + outbase + (size_t)j * 128 + d));
    }
    if (nv && hl < 7)
        __builtin_nontemporal_store((hl < deg) ? 1.0f : 0.0f, maskout + n * 7 + hl);
}

extern "C" void kernel_launch(void* const* d_in, const int* in_sizes, int n_in,
                              void* d_out, int out_size, void* d_ws, size_t ws_size,
                              hipStream_t stream) {
    const float* x   = (const float*)d_in[0];
    const float* w1  = (const float*)d_in[1];
    const float* b1  = (const float*)d_in[2];
    const float* w2  = (const float*)d_in[3];
    const float* b2  = (const float*)d_in[4];
    const float* wf  = (const float*)d_in[5];
    const float* bfv = (const float*)d_in[6];
    const int*   ci  = (const int*)d_in[7];

    int nrows = in_sizes[0] / 128;

    size_t gbytes = (size_t)2 * nrows * 128 * 2;
    unsigned short* g   = (unsigned short*)d_ws;
    unsigned short* wcT = (unsigned short*)((char*)d_ws + ((gbytes + 255) & ~(size_t)255));
    float*          cb  = (float*)((char*)wcT + 2 * 128 * 128 * 2);

    fuse_weights<<<2 * 129, 128, 0, stream>>>(w1, b1, w2, b2, wf, wcT, cb);

    int nblk = (nrows + 4 * WAVE_ROWS - 1) / (4 * WAVE_ROWS);
    gemm_g<<<nblk, 256, 0, stream>>>(x, wcT, cb, g, nrows);

    int rows = nrows * 7;
    int npairs = (nrows + 1) / 2;                 // 2 nodes per wave
    int cblk = (npairs * 64 + 255) / 256;
    float* out = (float*)d_out;
    gather_out<<<cblk, 256, 0, stream>>>(ci, g, bfv, out, out + (size_t)rows * 128, nrows);
}